// Round 1
// baseline (467.906 us; speedup 1.0000x reference)
//
#include <hip/hip_runtime.h>

#define BB 128
#define LL 256   // LQ == LA
#define DD 384

// ---------------- Phase 1: scores[b,q,a] = sum_d Q[b,q,d]*A[b,a,d] ----------------
__global__ __launch_bounds__(256) void scores_kernel(
    const float* __restrict__ qf, const float* __restrict__ af,
    float* __restrict__ sc)
{
  const int b  = blockIdx.z;
  const int q0 = blockIdx.x * 64;
  const int a0 = blockIdx.y * 64;
  __shared__ float sQ[32][68];   // [k][token], pad 68 -> 16B-aligned rows
  __shared__ float sA[32][68];
  const int t  = threadIdx.x;
  const int gr = t >> 4;         // 0..15 (4 q-rows each)
  const int gc = t & 15;         // 0..15 (4 a-cols each)
  float acc[4][4] = {};
  const float* qb = qf + ((size_t)b * LL + q0) * DD;
  const float* ab = af + ((size_t)b * LL + a0) * DD;
  const int col = t & 31, rt = t >> 5;
  for (int k0 = 0; k0 < DD; k0 += 32) {
    #pragma unroll
    for (int i = 0; i < 8; ++i) {
      int r = rt + i * 8;
      sQ[col][r] = qb[(size_t)r * DD + k0 + col];
      sA[col][r] = ab[(size_t)r * DD + k0 + col];
    }
    __syncthreads();
    #pragma unroll
    for (int kk = 0; kk < 32; ++kk) {
      float4 qv = *(const float4*)&sQ[kk][gr * 4];
      float4 av = *(const float4*)&sA[kk][gc * 4];
      const float* qp = (const float*)&qv;
      const float* ap = (const float*)&av;
      #pragma unroll
      for (int i = 0; i < 4; ++i)
        #pragma unroll
        for (int j = 0; j < 4; ++j)
          acc[i][j] = fmaf(qp[i], ap[j], acc[i][j]);
    }
    __syncthreads();
  }
  float* sb = sc + ((size_t)b * LL + q0 + gr * 4) * LL + a0 + gc * 4;
  #pragma unroll
  for (int i = 0; i < 4; ++i) {
    float4 v = make_float4(acc[i][0], acc[i][1], acc[i][2], acc[i][3]);
    *(float4*)&sb[(size_t)i * LL] = v;
  }
}

// ---------------- Phase 2: softmax + alpha@feat + per-token l2norm + masked pool ----------------
// side 0: rows are q tokens, softmax over a, feat=a_feat, self=q_feat, mask=q_mask
// side 1: rows are a tokens, softmax over q, feat=q_feat, self=a_feat, mask=a_mask
#define ROWS 32
#define DCH 128
#define KT 32

__global__ __launch_bounds__(256) void attend_pool_kernel(
    const float* __restrict__ qf, const float* __restrict__ af,
    const int* __restrict__ qm, const int* __restrict__ am,
    const float* __restrict__ sc, float* __restrict__ accum)
{
  const int b    = blockIdx.z;
  const int side = blockIdx.y;
  const int r0   = blockIdx.x * ROWS;
  const float* feat = side ? qf : af;
  const float* self = side ? af : qf;
  const int*   msk  = side ? am : qm;

  __shared__ float alpha[ROWS][260];   // pad 260 (16B-aligned rows)
  __shared__ float sF[KT][132];
  __shared__ float pool[2 * DD];

  const int t = threadIdx.x;
  for (int i = t; i < 2 * DD; i += 256) pool[i] = 0.f;

  // ---- load scores tile ----
  const float* sb = sc + (size_t)b * LL * LL;
  if (side == 0) {
    #pragma unroll
    for (int i = 0; i < 4; ++i) {
      int r = (t >> 5) + 8 * i;
      const float4* src = (const float4*)&sb[(size_t)(r0 + r) * LL];
      #pragma unroll
      for (int h = 0; h < 2; ++h) {
        int c4 = (t & 31) + 32 * h;
        *(float4*)&alpha[r][c4 * 4] = src[c4];
      }
    }
  } else {
    #pragma unroll 4
    for (int i = 0; i < 32; ++i) {
      int c = (t >> 5) + 8 * i;            // q index
      int r = t & 31;                      // a row
      alpha[r][c] = sb[(size_t)c * LL + r0 + r];
    }
  }
  __syncthreads();

  // ---- fp32 softmax per row (8 threads/row) ----
  {
    int r = t >> 3, s8 = t & 7;
    float m = -1e30f;
    for (int c = s8; c < LL; c += 8) m = fmaxf(m, alpha[r][c]);
    #pragma unroll
    for (int off = 1; off < 8; off <<= 1) m = fmaxf(m, __shfl_xor(m, off));
    float sum = 0.f;
    for (int c = s8; c < LL; c += 8) {
      float e = __expf(alpha[r][c] - m);
      alpha[r][c] = e;
      sum += e;
    }
    #pragma unroll
    for (int off = 1; off < 8; off <<= 1) sum += __shfl_xor(sum, off);
    float inv = 1.f / sum;
    for (int c = s8; c < LL; c += 8) alpha[r][c] *= inv;
  }
  __syncthreads();

  // ---- GEMM: attended[32,384] = alpha[32,256] @ feat[256,384] ----
  const int gr = t >> 5;   // 0..7 row-group (4 rows)
  const int gc = t & 31;   // 0..31 col-group (4 cols, 128/chunk)
  float qi[3][4][4] = {};
  #pragma unroll
  for (int ch = 0; ch < 3; ++ch) {
    const int d0 = ch * DCH;
    for (int k0 = 0; k0 < LL; k0 += KT) {
      #pragma unroll
      for (int i = 0; i < 4; ++i) {
        int kk = (t >> 5) + 8 * i;
        *(float4*)&sF[kk][(t & 31) * 4] =
            *(const float4*)&feat[((size_t)b * LL + k0 + kk) * DD + d0 + (t & 31) * 4];
      }
      __syncthreads();
      #pragma unroll
      for (int kk = 0; kk < KT; kk += 4) {
        float4 av[4];
        #pragma unroll
        for (int i = 0; i < 4; ++i)
          av[i] = *(const float4*)&alpha[gr * 4 + i][k0 + kk];
        #pragma unroll
        for (int m = 0; m < 4; ++m) {
          float4 fv = *(const float4*)&sF[kk + m][gc * 4];
          const float* fp = (const float*)&fv;
          #pragma unroll
          for (int i = 0; i < 4; ++i) {
            float w = ((const float*)&av[i])[m];
            #pragma unroll
            for (int j = 0; j < 4; ++j)
              qi[ch][i][j] = fmaf(w, fp[j], qi[ch][i][j]);
          }
        }
      }
      __syncthreads();
    }
  }

  // ---- per-row norm over [self, attended] (768 dims) ----
  float ssq[4] = {0.f, 0.f, 0.f, 0.f};
  #pragma unroll
  for (int ch = 0; ch < 3; ++ch)
    #pragma unroll
    for (int i = 0; i < 4; ++i)
      #pragma unroll
      for (int j = 0; j < 4; ++j)
        ssq[i] += qi[ch][i][j] * qi[ch][i][j];

  const float* selfb = self + ((size_t)b * LL + r0 + gr * 4) * DD;
  #pragma unroll
  for (int ch = 0; ch < 3; ++ch)
    #pragma unroll
    for (int i = 0; i < 4; ++i) {
      float4 v = *(const float4*)&selfb[(size_t)i * DD + ch * DCH + gc * 4];
      ssq[i] += v.x * v.x + v.y * v.y + v.z * v.z + v.w * v.w;
    }
  #pragma unroll
  for (int off = 1; off < 32; off <<= 1)
    #pragma unroll
    for (int i = 0; i < 4; ++i)
      ssq[i] += __shfl_xor(ssq[i], off);

  float inv[4];
  #pragma unroll
  for (int i = 0; i < 4; ++i) {
    int rr = r0 + gr * 4 + i;
    int mv = msk[(size_t)b * LL + rr];
    float n = sqrtf(ssq[i]);
    inv[i] = mv ? (1.f / fmaxf(n, 1e-12f)) : 0.f;
  }

  // ---- masked pooled accumulation (LDS, then one global flush) ----
  #pragma unroll
  for (int ch = 0; ch < 3; ++ch) {
    float aq[4] = {0.f, 0.f, 0.f, 0.f};
    float ai[4] = {0.f, 0.f, 0.f, 0.f};
    #pragma unroll
    for (int i = 0; i < 4; ++i) {
      float4 v = *(const float4*)&selfb[(size_t)i * DD + ch * DCH + gc * 4];
      aq[0] += v.x * inv[i]; aq[1] += v.y * inv[i];
      aq[2] += v.z * inv[i]; aq[3] += v.w * inv[i];
      #pragma unroll
      for (int j = 0; j < 4; ++j) ai[j] += qi[ch][i][j] * inv[i];
    }
    #pragma unroll
    for (int j = 0; j < 4; ++j) {
      int d = ch * DCH + gc * 4 + j;
      atomicAdd(&pool[d], aq[j]);
      atomicAdd(&pool[DD + d], ai[j]);
    }
  }
  __syncthreads();

  float* ac = accum + ((size_t)side * BB + b) * 2 * DD;
  for (int d = t; d < 2 * DD; d += 256)
    atomicAdd(&ac[d], pool[d]);
}

// ---------------- Phase 3: divide by mask count, final l2norm ----------------
__global__ __launch_bounds__(256) void finalize_kernel(
    const float* __restrict__ accum, const int* __restrict__ qm,
    const int* __restrict__ am, float* __restrict__ out)
{
  const int b    = blockIdx.x & (BB - 1);
  const int side = blockIdx.x >> 7;
  const int* msk = side ? am : qm;
  const int t = threadIdx.x;
  __shared__ float red[8];

  float c = (float)msk[(size_t)b * LL + t];
  #pragma unroll
  for (int off = 1; off < 64; off <<= 1) c += __shfl_xor(c, off);
  if ((t & 63) == 0) red[t >> 6] = c;
  __syncthreads();
  float cnt = fmaxf(red[0] + red[1] + red[2] + red[3], 1e-9f);

  const float* ac = accum + ((size_t)side * BB + b) * 2 * DD;
  float v[3];
  float ssq = 0.f;
  #pragma unroll
  for (int i = 0; i < 3; ++i) {
    v[i] = ac[t * 3 + i] / cnt;
    ssq += v[i] * v[i];
  }
  #pragma unroll
  for (int off = 1; off < 64; off <<= 1) ssq += __shfl_xor(ssq, off);
  __syncthreads();
  if ((t & 63) == 0) red[t >> 6] = ssq;
  __syncthreads();
  float n = sqrtf(red[0] + red[1] + red[2] + red[3]);
  float inv = 1.f / fmaxf(n, 1e-12f);
  float* ob = out + ((size_t)side * BB + b) * 2 * DD;
  #pragma unroll
  for (int i = 0; i < 3; ++i) ob[t * 3 + i] = v[i] * inv;
}

extern "C" void kernel_launch(void* const* d_in, const int* in_sizes, int n_in,
                              void* d_out, int out_size, void* d_ws, size_t ws_size,
                              hipStream_t stream) {
  const float* qf = (const float*)d_in[0];
  const float* af = (const float*)d_in[1];
  const int*   qm = (const int*)d_in[2];
  const int*   am = (const int*)d_in[3];
  float* out   = (float*)d_out;
  float* sc    = (float*)d_ws;                       // 128*256*256*4 = 33.55 MB
  float* accum = sc + (size_t)BB * LL * LL;          // 2*128*768*4  = 786 KB

  hipMemsetAsync(accum, 0, sizeof(float) * 2 * BB * 2 * DD, stream);
  scores_kernel<<<dim3(4, 4, BB), 256, 0, stream>>>(qf, af, sc);
  attend_pool_kernel<<<dim3(8, 2, BB), 256, 0, stream>>>(qf, af, qm, am, sc, accum);
  finalize_kernel<<<256, 256, 0, stream>>>(accum, qm, am, out);
}

// Round 2
// 258.380 us; speedup vs baseline: 1.8109x; 1.8109x over previous
//
#include <hip/hip_runtime.h>

#define BB 128
#define LL 256
#define DD 384
#define QB 64

typedef __attribute__((ext_vector_type(8))) short bf16x8;
typedef __attribute__((ext_vector_type(4))) short bf16x4;
typedef __attribute__((ext_vector_type(4))) float f32x4;

__device__ inline uint f2bf_rne(float x) {
  uint u = __float_as_uint(x);
  return (u + 0x7FFFu + ((u >> 16) & 1u)) >> 16;
}

// split fp32 -> bf16 hi (truncate) + bf16 lo (residual, truncate), 2 elems packed
__device__ inline void stage_hilo(const float* gp, short* hp, short* lp) {
  float2 x = *(const float2*)gp;
  uint x0 = __float_as_uint(x.x), x1 = __float_as_uint(x.y);
  uint hi = (x1 & 0xFFFF0000u) | (x0 >> 16);
  float l0f = x.x - __uint_as_float(x0 & 0xFFFF0000u);
  float l1f = x.y - __uint_as_float(x1 & 0xFFFF0000u);
  uint lo = (__float_as_uint(l1f) & 0xFFFF0000u) | (__float_as_uint(l0f) >> 16);
  *(uint*)hp = hi;
  *(uint*)lp = lo;
}

// 8-bf16 fragment from two ds_read_b64 (rows are 72B-strided, only 8B-aligned)
__device__ inline bf16x8 ld_frag8(const short* p) {
  bf16x4 lo = *(const bf16x4*)p;
  bf16x4 hi = *(const bf16x4*)(p + 4);
  bf16x8 r;
  r[0] = lo[0]; r[1] = lo[1]; r[2] = lo[2]; r[3] = lo[3];
  r[4] = hi[0]; r[5] = hi[1]; r[6] = hi[2]; r[7] = hi[3];
  return r;
}

// Fused: scores(split-bf16 MFMA) -> softmax -> PV(bf16 MFMA) -> row-l2norm -> masked pool
__global__ __launch_bounds__(512, 4) void fused_kernel(
    const float* __restrict__ qf, const float* __restrict__ af,
    const int* __restrict__ qm, const int* __restrict__ am,
    float* __restrict__ accum)
{
  const int b = blockIdx.z, side = blockIdx.y, r0 = blockIdx.x * QB;
  const float* self = side ? af : qf;   // rows we attend FROM
  const float* feat = side ? qf : af;   // rows we attend TO
  const int*   msk  = side ? am : qm;

  // LDS: 36864 + 4608*2 + 33280 + 1024 + 256 + 256 = 80896 B -> 2 blocks/CU
  __shared__ __align__(16) short sFbuf[2][LL][36];  // phase A: feat hi/lo k-slice; reused as featT
  __shared__ __align__(16) short sSh[QB][36];       // self hi slice
  __shared__ __align__(16) short sSl[QB][36];       // self lo slice
  __shared__ __align__(16) short sAl[QB][260];      // alpha bf16 [q][a]; tail reused as pool
  __shared__ float sRed[4][QB];
  __shared__ float sInv[QB];
  __shared__ float sSsqSelf[QB];

  short (*sFt)[36] = (short(*)[36])&sFbuf[0][0][0]; // featT[384][36] (27648B <= 36864B)
  float* sPoolA = (float*)&sAl[0][0];               // overlay, live only after PV

  const int t = threadIdx.x;
  const int w = t >> 6, lane = t & 63;
  const int lam = lane & 15, g = lane >> 4;
  const int wr = w >> 2, wc = w & 3;   // wave grid 2x4 over 64 rows x 256 cols

  // ---------------- Phase A: scores = self . feat^T (split bf16, 3 MFMAs) ----------------
  f32x4 accS[2][4] = {};
  for (int k0 = 0; k0 < DD; k0 += 32) {
    #pragma unroll
    for (int i = 0; i < 8; ++i) {            // feat[256][32] -> hi/lo
      int u = t + i * 512;
      int tok = u >> 4, kp = u & 15;
      stage_hilo(&feat[((size_t)b * LL + tok) * DD + k0 + kp * 2],
                 &sFbuf[0][tok][kp * 2], &sFbuf[1][tok][kp * 2]);
    }
    #pragma unroll
    for (int i = 0; i < 2; ++i) {            // self[64][32] -> hi/lo
      int u = t + i * 512;
      int tok = u >> 4, kp = u & 15;
      stage_hilo(&self[((size_t)b * LL + r0 + tok) * DD + k0 + kp * 2],
                 &sSh[tok][kp * 2], &sSl[tok][kp * 2]);
    }
    __syncthreads();
    bf16x8 ah[2], al[2];
    #pragma unroll
    for (int rt = 0; rt < 2; ++rt) {
      ah[rt] = ld_frag8(&sSh[wr * 32 + rt * 16 + lam][g * 8]);
      al[rt] = ld_frag8(&sSl[wr * 32 + rt * 16 + lam][g * 8]);
    }
    #pragma unroll
    for (int ct = 0; ct < 4; ++ct) {
      int tok = wc * 64 + ct * 16 + lam;
      bf16x8 bh = ld_frag8(&sFbuf[0][tok][g * 8]);
      bf16x8 bl = ld_frag8(&sFbuf[1][tok][g * 8]);
      #pragma unroll
      for (int rt = 0; rt < 2; ++rt) {
        accS[rt][ct] = __builtin_amdgcn_mfma_f32_16x16x32_bf16(ah[rt], bh, accS[rt][ct], 0, 0, 0);
        accS[rt][ct] = __builtin_amdgcn_mfma_f32_16x16x32_bf16(ah[rt], bl, accS[rt][ct], 0, 0, 0);
        accS[rt][ct] = __builtin_amdgcn_mfma_f32_16x16x32_bf16(al[rt], bh, accS[rt][ct], 0, 0, 0);
      }
    }
    __syncthreads();
  }

  // ---------------- Softmax over cols (C layout: col=lane&15, row=g*4+reg) ----------------
  float mrow[2][4];
  #pragma unroll
  for (int rt = 0; rt < 2; ++rt)
    #pragma unroll
    for (int rg = 0; rg < 4; ++rg) {
      float m = fmaxf(fmaxf(accS[rt][0][rg], accS[rt][1][rg]),
                      fmaxf(accS[rt][2][rg], accS[rt][3][rg]));
      #pragma unroll
      for (int off = 1; off < 16; off <<= 1) m = fmaxf(m, __shfl_xor(m, off));
      mrow[rt][rg] = m;
      if (lam == 0) sRed[wc][wr * 32 + rt * 16 + g * 4 + rg] = m;
    }
  __syncthreads();
  #pragma unroll
  for (int rt = 0; rt < 2; ++rt)
    #pragma unroll
    for (int rg = 0; rg < 4; ++rg) {
      int row = wr * 32 + rt * 16 + g * 4 + rg;
      mrow[rt][rg] = fmaxf(fmaxf(sRed[0][row], sRed[1][row]),
                           fmaxf(sRed[2][row], sRed[3][row]));
    }
  __syncthreads();   // all reads of sRed(max) done before reuse
  #pragma unroll
  for (int rt = 0; rt < 2; ++rt)
    #pragma unroll
    for (int rg = 0; rg < 4; ++rg) {
      float s = 0.f;
      #pragma unroll
      for (int ct = 0; ct < 4; ++ct) {
        float p = __expf(accS[rt][ct][rg] - mrow[rt][rg]);
        accS[rt][ct][rg] = p;
        s += p;
      }
      #pragma unroll
      for (int off = 1; off < 16; off <<= 1) s += __shfl_xor(s, off);
      if (lam == 0) sRed[wc][wr * 32 + rt * 16 + g * 4 + rg] = s;
    }
  __syncthreads();
  #pragma unroll
  for (int rt = 0; rt < 2; ++rt)
    #pragma unroll
    for (int rg = 0; rg < 4; ++rg) {
      int row = wr * 32 + rt * 16 + g * 4 + rg;
      float inv = 1.f / (sRed[0][row] + sRed[1][row] + sRed[2][row] + sRed[3][row]);
      #pragma unroll
      for (int ct = 0; ct < 4; ++ct) {
        int col = wc * 64 + ct * 16 + lam;
        sAl[row][col] = (short)f2bf_rne(accS[rt][ct][rg] * inv);
      }
    }
  __syncthreads();

  // ---------------- PV: attended = alpha[64][256] @ feat[256][384] ----------------
  f32x4 accP[2][6] = {};
  for (int k0 = 0; k0 < LL; k0 += 32) {
    #pragma unroll
    for (int i = 0; i < 12; ++i) {           // transpose-stage featT[d][k]
      int u = t + i * 512;
      int kp = u / 384, d = u - kp * 384;
      const float* fp = &feat[((size_t)b * LL + k0 + kp * 2) * DD + d];
      uint pk = f2bf_rne(fp[0]) | (f2bf_rne(fp[DD]) << 16);
      *(uint*)&sFt[d][kp * 2] = pk;
    }
    __syncthreads();
    bf16x8 pa[2];
    #pragma unroll
    for (int rt = 0; rt < 2; ++rt)
      pa[rt] = ld_frag8(&sAl[wr * 32 + rt * 16 + lam][k0 + g * 8]);
    #pragma unroll
    for (int dt = 0; dt < 6; ++dt) {
      bf16x8 fb = ld_frag8(&sFt[wc * 96 + dt * 16 + lam][g * 8]);
      #pragma unroll
      for (int rt = 0; rt < 2; ++rt)
        accP[rt][dt] = __builtin_amdgcn_mfma_f32_16x16x32_bf16(pa[rt], fb, accP[rt][dt], 0, 0, 0);
    }
    __syncthreads();
  }

  // ---------------- Epilogue: row l2norm over [self|attended], masked pool ----------------
  #pragma unroll
  for (int rt = 0; rt < 2; ++rt)
    #pragma unroll
    for (int rg = 0; rg < 4; ++rg) {
      float s = 0.f;
      #pragma unroll
      for (int dt = 0; dt < 6; ++dt) s += accP[rt][dt][rg] * accP[rt][dt][rg];
      #pragma unroll
      for (int off = 1; off < 16; off <<= 1) s += __shfl_xor(s, off);
      if (lam == 0) sRed[wc][wr * 32 + rt * 16 + g * 4 + rg] = s;
    }
  {
    int sr = t >> 3, sc = (t & 7) * 4;
    const float* sp = &self[((size_t)b * LL + r0 + sr) * DD];
    float ss = 0.f;
    #pragma unroll
    for (int j = 0; j < 12; ++j) {
      float4 v = *(const float4*)&sp[sc + j * 32];
      ss += v.x * v.x + v.y * v.y + v.z * v.z + v.w * v.w;
    }
    ss += __shfl_xor(ss, 1); ss += __shfl_xor(ss, 2); ss += __shfl_xor(ss, 4);
    if ((t & 7) == 0) sSsqSelf[sr] = ss;
  }
  if (t < DD) sPoolA[t] = 0.f;   // sAl dead -> pool buffer
  __syncthreads();
  if (t < QB) {
    float tot = sSsqSelf[t] + sRed[0][t] + sRed[1][t] + sRed[2][t] + sRed[3][t];
    int mv = msk[(size_t)b * LL + r0 + t];
    sInv[t] = mv ? (1.f / fmaxf(sqrtf(tot), 1e-12f)) : 0.f;
  }
  __syncthreads();
  #pragma unroll
  for (int dt = 0; dt < 6; ++dt) {
    float pa = 0.f;
    #pragma unroll
    for (int rt = 0; rt < 2; ++rt)
      #pragma unroll
      for (int rg = 0; rg < 4; ++rg)
        pa += sInv[wr * 32 + rt * 16 + g * 4 + rg] * accP[rt][dt][rg];
    pa += __shfl_xor(pa, 16);
    pa += __shfl_xor(pa, 32);
    if (g == 0) atomicAdd(&sPoolA[wc * 96 + dt * 16 + lam], pa);
  }
  __syncthreads();
  if (t < DD) {
    float* ac = accum + ((size_t)side * BB + b) * 2 * DD;
    float ps = 0.f;
    const float* sp = &self[((size_t)b * LL + r0) * DD + t];
    #pragma unroll 4
    for (int r = 0; r < QB; ++r) ps = fmaf(sInv[r], sp[(size_t)r * DD], ps);
    atomicAdd(&ac[t], ps);
    atomicAdd(&ac[DD + t], sPoolA[t]);
  }
}

// ---------------- Finalize: divide by mask count, final l2norm ----------------
__global__ __launch_bounds__(256) void finalize_kernel(
    const float* __restrict__ accum, const int* __restrict__ qm,
    const int* __restrict__ am, float* __restrict__ out)
{
  const int b    = blockIdx.x & (BB - 1);
  const int side = blockIdx.x >> 7;
  const int* msk = side ? am : qm;
  const int t = threadIdx.x;
  __shared__ float red[8];

  float c = (float)msk[(size_t)b * LL + t];
  #pragma unroll
  for (int off = 1; off < 64; off <<= 1) c += __shfl_xor(c, off);
  if ((t & 63) == 0) red[t >> 6] = c;
  __syncthreads();
  float cnt = fmaxf(red[0] + red[1] + red[2] + red[3], 1e-9f);

  const float* ac = accum + ((size_t)side * BB + b) * 2 * DD;
  float v[3];
  float ssq = 0.f;
  #pragma unroll
  for (int i = 0; i < 3; ++i) {
    v[i] = ac[t * 3 + i] / cnt;
    ssq += v[i] * v[i];
  }
  #pragma unroll
  for (int off = 1; off < 64; off <<= 1) ssq += __shfl_xor(ssq, off);
  __syncthreads();
  if ((t & 63) == 0) red[t >> 6] = ssq;
  __syncthreads();
  float n = sqrtf(red[0] + red[1] + red[2] + red[3]);
  float inv = 1.f / fmaxf(n, 1e-12f);
  float* ob = out + ((size_t)side * BB + b) * 2 * DD;
  #pragma unroll
  for (int i = 0; i < 3; ++i) ob[t * 3 + i] = v[i] * inv;
}

extern "C" void kernel_launch(void* const* d_in, const int* in_sizes, int n_in,
                              void* d_out, int out_size, void* d_ws, size_t ws_size,
                              hipStream_t stream) {
  const float* qf = (const float*)d_in[0];
  const float* af = (const float*)d_in[1];
  const int*   qm = (const int*)d_in[2];
  const int*   am = (const int*)d_in[3];
  float* out   = (float*)d_out;
  float* accum = (float*)d_ws;   // 2*128*768*4 = 786 KB

  hipMemsetAsync(accum, 0, sizeof(float) * 2 * BB * 2 * DD, stream);
  fused_kernel<<<dim3(LL / QB, 2, BB), 512, 0, stream>>>(qf, af, qm, am, accum);
  finalize_kernel<<<256, 256, 0, stream>>>(accum, qm, am, out);
}